// Round 10
// baseline (525.793 us; speedup 1.0000x reference)
//
#include <hip/hip_runtime.h>
#include <math.h>

#define NN 50000
#define NF 512
#define NH 128
#define NC 10
#define NE 800000

typedef __attribute__((ext_vector_type(8))) short short8_t;
typedef __attribute__((ext_vector_type(4))) float f32x4;

__device__ inline ushort f2bf(float f) {
    union { float f; uint u; } v;
    v.f = f;
    uint r = v.u + 0x7FFF + ((v.u >> 16) & 1);
    return (ushort)(r >> 16);
}
__device__ inline uint pk2(float a, float b) {
    return (uint)f2bf(a) | ((uint)f2bf(b) << 16);
}
__device__ inline float bflo(uint u) {
    union { uint u; float f; } v;
    v.u = u << 16;
    return v.f;
}
__device__ inline float bfhi(uint u) {
    union { uint u; float f; } v;
    v.u = u & 0xFFFF0000u;
    return v.f;
}

// Block-local int64-vs-int32 detection
__device__ inline int detect_i64(const int* __restrict__ ei) {
    __shared__ int s_nz;
    if (threadIdx.x == 0) s_nz = 0;
    __syncthreads();
    int v = 0;
    for (int i = threadIdx.x; i < 1024; i += 256) v |= ei[2 * i + 1];
    if (v) s_nz = 1;  // benign race
    __syncthreads();
    return (s_nz == 0) ? 1 : 0;
}

// ---------------- degree count ----------------
__global__ __launch_bounds__(256) void deg_direct_kernel(const int* __restrict__ ei,
                                                         int* __restrict__ deg) {
    const int i64 = detect_i64(ei);
    int e = blockIdx.x * 256 + threadIdx.x;
    if (e >= NE) return;
    int d = i64 ? ei[2 * (NE + e)] : ei[NE + e];
    d = min(max(d, 0), NN - 1);
    atomicAdd(&deg[d], 1);
}

// ---------------- prefix sum -> row_ptr (+dinv) ----------------
#define SCAN_ELEMS 2048
#define SCAN_BLOCKS ((NN + SCAN_ELEMS - 1) / SCAN_ELEMS)  // 25

__global__ __launch_bounds__(256) void scan1_kernel(const int* __restrict__ deg,
                                                    int* __restrict__ row_ptr,
                                                    int* __restrict__ block_sums,
                                                    float* __restrict__ dinv) {
    __shared__ int ldata[256];
    const int t = threadIdx.x;
    const int base = blockIdx.x * SCAN_ELEMS;
    int v[8];
    int sum = 0;
#pragma unroll
    for (int j = 0; j < 8; ++j) {
        int idx = base + t * 8 + j;
        v[j] = (idx < NN) ? deg[idx] : 0;
        if (idx < NN) dinv[idx] = rsqrtf((float)v[j] + 1.0f);  // +1 self-loop
        sum += v[j];
    }
    ldata[t] = sum;
    __syncthreads();
    for (int off = 1; off < 256; off <<= 1) {
        int x = (t >= off) ? ldata[t - off] : 0;
        __syncthreads();
        if (t >= off) ldata[t] += x;
        __syncthreads();
    }
    int excl = ldata[t] - sum;
    if (t == 255) block_sums[blockIdx.x] = ldata[255];
    int run = excl;
#pragma unroll
    for (int j = 0; j < 8; ++j) {
        int idx = base + t * 8 + j;
        if (idx < NN) row_ptr[idx] = run;
        run += v[j];
    }
}

__global__ __launch_bounds__(256) void scan3_kernel(int* __restrict__ row_ptr,
                                                    const int* __restrict__ block_sums) {
    int add = 0;
    for (int i = 0; i < SCAN_BLOCKS; ++i) add += (i < blockIdx.x) ? block_sums[i] : 0;
    const int base = blockIdx.x * SCAN_ELEMS;
#pragma unroll
    for (int j = 0; j < 8; ++j) {
        int idx = base + threadIdx.x * 8 + j;
        if (idx < NN) row_ptr[idx] += add;
    }
    if (blockIdx.x == 0 && threadIdx.x == 0) row_ptr[NN] = NE;
}

// ---------------- fill CSR (ushort src only; weight recomputed later) ----------------
__global__ __launch_bounds__(256) void fill_direct_kernel(const int* __restrict__ ei,
                                                          const int* __restrict__ row_ptr,
                                                          int* __restrict__ fill,
                                                          ushort* __restrict__ csr_src) {
    const int i64 = detect_i64(ei);
    int e = blockIdx.x * 256 + threadIdx.x;
    if (e >= NE) return;
    int s = i64 ? ei[2 * e] : ei[e];
    int d = i64 ? ei[2 * (NE + e)] : ei[NE + e];
    s = min(max(s, 0), NN - 1);
    d = min(max(d, 0), NN - 1);
    int pos = atomicAdd(&fill[d], 1);
    csr_src[row_ptr[d] + pos] = (ushort)s;
}

// ---------------- weight transpose + bf16 convert, all 3 weights ----------------
__global__ __launch_bounds__(128) void wtrans_all_kernel(
    const float* __restrict__ W1, const float* __restrict__ W2, const float* __restrict__ W3,
    ushort* __restrict__ Wt1, ushort* __restrict__ Wt2, ushort* __restrict__ Wt3) {
    __shared__ float tile[8][132];
    const int b = blockIdx.x;
    const float* W;
    ushort* Wt;
    int K, k0;
    if (b < 64) {
        W = W1; Wt = Wt1; K = NF; k0 = b * 8;
    } else if (b < 80) {
        W = W2; Wt = Wt2; K = NH; k0 = (b - 64) * 8;
    } else {
        W = W3; Wt = Wt3; K = NH; k0 = (b - 80) * 8;
    }
#pragma unroll
    for (int i = 0; i < 8; ++i) {
        int idx = threadIdx.x + i * 128;
        int r = idx >> 7;
        int c = idx & 127;
        tile[r][c] = W[(size_t)(k0 + r) * NH + c];
    }
    __syncthreads();
    const int c = threadIdx.x;
    uint4 o;
    o.x = pk2(tile[0][c], tile[1][c]);
    o.y = pk2(tile[2][c], tile[3][c]);
    o.z = pk2(tile[4][c], tile[5][c]);
    o.w = pk2(tile[6][c], tile[7][c]);
    *(uint4*)&Wt[(size_t)c * K + k0] = o;
}

// ---------------- MFMA GEMM ----------------
// A_MODE: 1 = f32 row-major input; 0 = bf16 plane-split [8][NN][16] input.
// OUT_ROW: 1 = bf16 row-major [NN][128] out; 0 = bf16 plane-split [8][NN][16] out.
#define BM 32

template <int A_MODE, int OUT_ROW>
__global__ __launch_bounds__(256) void gemm_mfma_kernel(const void* __restrict__ Ap,
                                                        const ushort* __restrict__ Wt,
                                                        ushort* __restrict__ Hout, int nrows,
                                                        int K) {
    __shared__ __align__(16) ushort smem[BM * 64 + NH * 64];
    ushort* As = smem;            // [32][64] bf16, swizzled
    ushort* Bs = smem + BM * 64;  // [128][64] bf16, swizzled
    const int tid = threadIdx.x;
    const int wave = tid >> 6;
    const int lane = tid & 63;
    const int l15 = lane & 15;
    const int l4 = lane >> 4;
    const int brow = blockIdx.x * BM;

    f32x4 zero4 = {0.f, 0.f, 0.f, 0.f};
    f32x4 acc[2][2];
#pragma unroll
    for (int rb = 0; rb < 2; ++rb)
#pragma unroll
        for (int cb = 0; cb < 2; ++cb) acc[rb][cb] = zero4;

    for (int k0 = 0; k0 < K; k0 += 64) {
        // stage A tile: 32 rows x 8 chunks(16B), one chunk per thread
        {
            int r = tid >> 3;
            int s = tid & 7;
            int gr = brow + r;
            uint4 w = make_uint4(0, 0, 0, 0);
            if (A_MODE) {
                if (gr < nrows) {
                    const float* A = (const float*)Ap;
                    float4 f0 = *(const float4*)(A + (size_t)gr * K + k0 + s * 8);
                    float4 f1 = *(const float4*)(A + (size_t)gr * K + k0 + s * 8 + 4);
                    w.x = pk2(f0.x, f0.y);
                    w.y = pk2(f0.z, f0.w);
                    w.z = pk2(f1.x, f1.y);
                    w.w = pk2(f1.z, f1.w);
                }
            } else {
                if (gr < nrows) {
                    const ushort* A = (const ushort*)Ap;
                    int plane = (k0 >> 4) + (s >> 1);
                    w = *(const uint4*)&A[((size_t)plane * NN + gr) * 16 + (s & 1) * 8];
                }
            }
            *(uint4*)&As[r * 64 + ((s ^ (r & 7)) * 8)] = w;
        }
        // stage B tile: 128 rows x 8 chunks, 4 chunks per thread
#pragma unroll
        for (int i = 0; i < 4; ++i) {
            int idx = tid + i * 256;
            int r = idx >> 3;
            int s = idx & 7;
            uint4 w = *(const uint4*)&Wt[(size_t)r * K + k0 + s * 8];
            *(uint4*)&Bs[r * 64 + ((s ^ (r & 7)) * 8)] = w;
        }
        __syncthreads();
#pragma unroll
        for (int ks = 0; ks < 2; ++ks) {
            short8_t af[2], bf[2];
#pragma unroll
            for (int rb = 0; rb < 2; ++rb) {
                int r = rb * 16 + l15;
                af[rb] = *(const short8_t*)&As[r * 64 + (((ks * 4 + l4) ^ (r & 7)) * 8)];
            }
#pragma unroll
            for (int cb = 0; cb < 2; ++cb) {
                int r = wave * 32 + cb * 16 + l15;
                bf[cb] = *(const short8_t*)&Bs[r * 64 + (((ks * 4 + l4) ^ (r & 7)) * 8)];
            }
#pragma unroll
            for (int rb = 0; rb < 2; ++rb)
#pragma unroll
                for (int cb = 0; cb < 2; ++cb)
                    acc[rb][cb] = __builtin_amdgcn_mfma_f32_16x16x32_bf16(af[rb], bf[cb],
                                                                          acc[rb][cb], 0, 0, 0);
        }
        __syncthreads();
    }

    // epilogue: assemble bf16 tile in LDS [32][136], then store
    ushort* Es = smem;
#pragma unroll
    for (int rb = 0; rb < 2; ++rb)
#pragma unroll
        for (int cb = 0; cb < 2; ++cb)
#pragma unroll
            for (int j = 0; j < 4; ++j) {
                int r = rb * 16 + l4 * 4 + j;
                int c = wave * 32 + cb * 16 + l15;
                Es[r * 136 + c] = f2bf(acc[rb][cb][j]);
            }
    __syncthreads();
#pragma unroll
    for (int i = 0; i < 2; ++i) {
        int idx = tid + i * 256;
        int r = idx >> 4;
        int s = idx & 15;
        if (brow + r < nrows) {
            uint4 w = *(const uint4*)&Es[r * 136 + s * 8];
            if (OUT_ROW) {
                *(uint4*)&Hout[(size_t)(brow + r) * NH + s * 8] = w;
            } else {
                int plane = s >> 1;
                *(uint4*)&Hout[((size_t)plane * NN + brow + r) * 16 + (s & 1) * 8] = w;
            }
        }
    }
}

__device__ inline void fma8(float* acc, float w, uint4 v) {
    acc[0] += w * bflo(v.x);
    acc[1] += w * bfhi(v.x);
    acc[2] += w * bflo(v.y);
    acc[3] += w * bfhi(v.y);
    acc[4] += w * bflo(v.z);
    acc[5] += w * bfhi(v.z);
    acc[6] += w * bflo(v.w);
    acc[7] += w * bfhi(v.w);
}

// ---------------- plane-split aggregate (layers 1,2) ----------------
// Plane p = blockIdx&7 (XCD-pinned on round-robin mapping). 32 edge-groups x 2 lanes;
// each wave = one node's 16-feature plane slice. relu + bias + self-loop fused.
__global__ __launch_bounds__(512) void aggregate_e_kernel(
    const ushort* __restrict__ hq, const int* __restrict__ row_ptr,
    const ushort* __restrict__ csr_src, const float* __restrict__ dinv,
    const float* __restrict__ b, ushort* __restrict__ actq) {
    const int p = blockIdx.x & 7;
    const int node = ((blockIdx.x >> 3) << 3) + (threadIdx.x >> 6);
    const int lane = threadIdx.x & 63;
    const int g = lane >> 1;   // edge group 0..31
    const int ci = lane & 1;   // 16B chunk within 32B plane-row
    const uint4* __restrict__ hp = (const uint4*)(hq + (size_t)p * NN * 16);
    const int beg = row_ptr[node];
    const int end = row_ptr[node + 1];
    const float dn = dinv[node];

    float acc[8];
#pragma unroll
    for (int k = 0; k < 8; ++k) acc[k] = 0.f;

    for (int e0 = beg; e0 < end; e0 += 32) {
        int e = e0 + g;
        if (e < end) {
            int s = csr_src[e];
            float w = dinv[s] * dn;
            uint4 v = hp[(size_t)s * 2 + ci];
            fma8(acc, w, v);
        }
    }
#pragma unroll
    for (int k = 0; k < 8; ++k) {
        acc[k] += __shfl_xor(acc[k], 2);
        acc[k] += __shfl_xor(acc[k], 4);
        acc[k] += __shfl_xor(acc[k], 8);
        acc[k] += __shfl_xor(acc[k], 16);
        acc[k] += __shfl_xor(acc[k], 32);
    }
    if (g == 0) {  // lanes 0,1
        uint4 hv = hp[(size_t)node * 2 + ci];
        float sl = dn * dn;
        const float* bb = b + p * 16 + ci * 8;
        float4 b0 = *(const float4*)(bb);
        float4 b1 = *(const float4*)(bb + 4);
        float v0 = fmaxf(acc[0] + sl * bflo(hv.x) + b0.x, 0.f);
        float v1 = fmaxf(acc[1] + sl * bfhi(hv.x) + b0.y, 0.f);
        float v2 = fmaxf(acc[2] + sl * bflo(hv.y) + b0.z, 0.f);
        float v3 = fmaxf(acc[3] + sl * bfhi(hv.y) + b0.w, 0.f);
        float v4 = fmaxf(acc[4] + sl * bflo(hv.z) + b1.x, 0.f);
        float v5 = fmaxf(acc[5] + sl * bfhi(hv.z) + b1.y, 0.f);
        float v6 = fmaxf(acc[6] + sl * bflo(hv.w) + b1.z, 0.f);
        float v7 = fmaxf(acc[7] + sl * bfhi(hv.w) + b1.w, 0.f);
        uint4 o;
        o.x = pk2(v0, v1);
        o.y = pk2(v2, v3);
        o.z = pk2(v4, v5);
        o.w = pk2(v6, v7);
        *(uint4*)&actq[((size_t)p * NN + node) * 16 + ci * 8] = o;
    }
}

// ---------------- full-row aggregate + classifier + log_softmax (layer 3) -------------
__global__ __launch_bounds__(256) void aggregate_final_kernel(
    const ushort* __restrict__ h, const int* __restrict__ row_ptr,
    const ushort* __restrict__ csr_src, const float* __restrict__ dinv,
    const float* __restrict__ b, const float* __restrict__ Wl, const float* __restrict__ bl,
    float* __restrict__ outp) {
    __shared__ float Wls[NH * NC + NC];
    for (int i = threadIdx.x; i < NH * NC; i += 256) Wls[i] = Wl[i];
    if (threadIdx.x < NC) Wls[NH * NC + threadIdx.x] = bl[threadIdx.x];
    __syncthreads();
    const int node = (blockIdx.x * 256 + threadIdx.x) >> 6;  // one wave per node
    if (node >= NN) return;
    const int lane = threadIdx.x & 63;
    const int g = lane >> 4;    // edge group 0..3
    const int li = lane & 15;   // feature chunk (8 bf16)
    const uint4* __restrict__ hp = (const uint4*)h;
    const int beg = row_ptr[node];
    const int end = row_ptr[node + 1];
    const float dn = dinv[node];

    float acc[8];
#pragma unroll
    for (int k = 0; k < 8; ++k) acc[k] = 0.f;

    for (int e0 = beg; e0 < end; e0 += 16) {
        int eb = e0 + g * 4;
        if (eb < end) {
            int s0 = min((int)csr_src[eb + 0], NN - 1);
            int s1 = min((int)csr_src[eb + 1], NN - 1);
            int s2 = min((int)csr_src[eb + 2], NN - 1);
            int s3 = min((int)csr_src[eb + 3], NN - 1);
            float w0 = dinv[s0] * dn;
            float w1 = (eb + 1 < end) ? dinv[s1] * dn : 0.f;
            float w2 = (eb + 2 < end) ? dinv[s2] * dn : 0.f;
            float w3 = (eb + 3 < end) ? dinv[s3] * dn : 0.f;
            uint4 v0 = hp[(size_t)s0 * 16 + li];
            uint4 v1 = hp[(size_t)s1 * 16 + li];
            uint4 v2 = hp[(size_t)s2 * 16 + li];
            uint4 v3 = hp[(size_t)s3 * 16 + li];
            fma8(acc, w0, v0);
            fma8(acc, w1, v1);
            fma8(acc, w2, v2);
            fma8(acc, w3, v3);
        }
    }
#pragma unroll
    for (int k = 0; k < 8; ++k) {
        acc[k] += __shfl_xor(acc[k], 16);
        acc[k] += __shfl_xor(acc[k], 32);
    }
    if (g == 0) {
        uint4 hv = hp[(size_t)node * 16 + li];
        float sl = dn * dn;
        float v[8];
        float4 b0 = *(const float4*)(b + li * 8);
        float4 b1 = *(const float4*)(b + li * 8 + 4);
        v[0] = acc[0] + sl * bflo(hv.x) + b0.x;
        v[1] = acc[1] + sl * bfhi(hv.x) + b0.y;
        v[2] = acc[2] + sl * bflo(hv.y) + b0.z;
        v[3] = acc[3] + sl * bfhi(hv.y) + b0.w;
        v[4] = acc[4] + sl * bflo(hv.z) + b1.x;
        v[5] = acc[5] + sl * bfhi(hv.z) + b1.y;
        v[6] = acc[6] + sl * bflo(hv.w) + b1.z;
        v[7] = acc[7] + sl * bfhi(hv.w) + b1.w;
        float lg[NC];
#pragma unroll
        for (int c = 0; c < NC; ++c) lg[c] = 0.f;
#pragma unroll
        for (int j = 0; j < 8; ++j) {
            int f = li * 8 + j;
#pragma unroll
            for (int c = 0; c < NC; ++c) lg[c] += v[j] * Wls[f * NC + c];
        }
#pragma unroll
        for (int c = 0; c < NC; ++c) {
            lg[c] += __shfl_xor(lg[c], 1);
            lg[c] += __shfl_xor(lg[c], 2);
            lg[c] += __shfl_xor(lg[c], 4);
            lg[c] += __shfl_xor(lg[c], 8);
            lg[c] += Wls[NH * NC + c];
        }
        float m = lg[0];
#pragma unroll
        for (int c = 1; c < NC; ++c) m = fmaxf(m, lg[c]);
        float s = 0.f;
#pragma unroll
        for (int c = 0; c < NC; ++c) s += expf(lg[c] - m);
        float lse = m + logf(s);
        if (li < NC) outp[(size_t)node * NC + li] = lg[li] - lse;
    }
}

extern "C" void kernel_launch(void* const* d_in, const int* in_sizes, int n_in,
                              void* d_out, int out_size, void* d_ws, size_t ws_size,
                              hipStream_t stream) {
    const float* x = (const float*)d_in[0];
    const int* ei = (const int*)d_in[1];
    const float* W1 = (const float*)d_in[2];
    const float* b1 = (const float*)d_in[3];
    const float* W2 = (const float*)d_in[4];
    const float* b2 = (const float*)d_in[5];
    const float* W3 = (const float*)d_in[6];
    const float* b3 = (const float*)d_in[7];
    const float* Wl = (const float*)d_in[8];
    const float* bl = (const float*)d_in[9];
    float* out = (float*)d_out;

    char* ws = (char*)d_ws;
    size_t off = 0;
    auto alloc = [&](size_t bytes) {
        void* p = ws + off;
        off = (off + bytes + 255) & ~(size_t)255;
        return p;
    };
    int* degfill = (int*)alloc((size_t)2 * NN * 4);  // deg | fill, one memset
    int* deg = degfill;
    int* fill = degfill + NN;
    float* dinv = (float*)alloc((size_t)NN * 4);
    int* row_ptr = (int*)alloc((size_t)(NN + 1) * 4);
    int* block_sums = (int*)alloc((size_t)SCAN_BLOCKS * 4 + 256);
    ushort* csr_src = (ushort*)alloc((size_t)(NE + 32) * 2);  // src only, +pad
    ushort* h = (ushort*)alloc((size_t)NN * NH * 2);     // planes [8][NN][16]; layer-3 row-major
    ushort* act = (ushort*)alloc((size_t)NN * NH * 2);   // planes [8][NN][16]
    ushort* Wt1 = (ushort*)alloc((size_t)NF * NH * 2);
    ushort* Wt2 = (ushort*)alloc((size_t)NH * NH * 2);
    ushort* Wt3 = (ushort*)alloc((size_t)NH * NH * 2);
    (void)ws_size;

    // --- CSR build (once, reused for 3 layers) ---
    hipMemsetAsync(degfill, 0, (size_t)2 * NN * 4, stream);
    deg_direct_kernel<<<(NE + 255) / 256, 256, 0, stream>>>(ei, deg);
    scan1_kernel<<<SCAN_BLOCKS, 256, 0, stream>>>(deg, row_ptr, block_sums, dinv);
    scan3_kernel<<<SCAN_BLOCKS, 256, 0, stream>>>(row_ptr, block_sums);
    fill_direct_kernel<<<(NE + 255) / 256, 256, 0, stream>>>(ei, row_ptr, fill, csr_src);
    wtrans_all_kernel<<<96, 128, 0, stream>>>(W1, W2, W3, Wt1, Wt2, Wt3);

    const int gemm_grid = (NN + BM - 1) / BM;
    const int agge_grid = (NN / 8) * 8;  // 50000 blocks: plane = b&7, 8 nodes per block

    // layer 1: h planes = x @ W1 ; act planes = relu(agg + selfloop + b1)
    gemm_mfma_kernel<1, 0><<<gemm_grid, 256, 0, stream>>>(x, Wt1, h, NN, NF);
    aggregate_e_kernel<<<agge_grid, 512, 0, stream>>>(h, row_ptr, csr_src, dinv, b1, act);
    // layer 2
    gemm_mfma_kernel<0, 0><<<gemm_grid, 256, 0, stream>>>(act, Wt2, h, NN, NH);
    aggregate_e_kernel<<<agge_grid, 512, 0, stream>>>(h, row_ptr, csr_src, dinv, b2, act);
    // layer 3: gemm -> row-major h; fused aggregate + classifier + log_softmax
    gemm_mfma_kernel<0, 1><<<gemm_grid, 256, 0, stream>>>(act, Wt3, h, NN, NH);
    aggregate_final_kernel<<<(NN * 64 + 255) / 256, 256, 0, stream>>>(h, row_ptr, csr_src,
                                                                      dinv, b3, Wl, bl, out);
}

// Round 11
// 269.243 us; speedup vs baseline: 1.9529x; 1.9529x over previous
//
#include <hip/hip_runtime.h>
#include <math.h>

#define NN 50000
#define NF 512
#define NH 128
#define NC 10
#define NE 800000

typedef __attribute__((ext_vector_type(8))) short short8_t;
typedef __attribute__((ext_vector_type(4))) float f32x4;

__device__ inline ushort f2bf(float f) {
    union { float f; uint u; } v;
    v.f = f;
    uint r = v.u + 0x7FFF + ((v.u >> 16) & 1);
    return (ushort)(r >> 16);
}
__device__ inline uint pk2(float a, float b) {
    return (uint)f2bf(a) | ((uint)f2bf(b) << 16);
}
__device__ inline float bflo(uint u) {
    union { uint u; float f; } v;
    v.u = u << 16;
    return v.f;
}
__device__ inline float bfhi(uint u) {
    union { uint u; float f; } v;
    v.u = u & 0xFFFF0000u;
    return v.f;
}

// Block-local int64-vs-int32 detection
__device__ inline int detect_i64(const int* __restrict__ ei) {
    __shared__ int s_nz;
    if (threadIdx.x == 0) s_nz = 0;
    __syncthreads();
    int v = 0;
    for (int i = threadIdx.x; i < 1024; i += 256) v |= ei[2 * i + 1];
    if (v) s_nz = 1;  // benign race
    __syncthreads();
    return (s_nz == 0) ? 1 : 0;
}

// ---------------- degree count ----------------
__global__ __launch_bounds__(256) void deg_direct_kernel(const int* __restrict__ ei,
                                                         int* __restrict__ deg) {
    const int i64 = detect_i64(ei);
    int e = blockIdx.x * 256 + threadIdx.x;
    if (e >= NE) return;
    int d = i64 ? ei[2 * (NE + e)] : ei[NE + e];
    d = min(max(d, 0), NN - 1);
    atomicAdd(&deg[d], 1);
}

// ---------------- prefix sum -> row_ptr (+dinv) ----------------
#define SCAN_ELEMS 2048
#define SCAN_BLOCKS ((NN + SCAN_ELEMS - 1) / SCAN_ELEMS)  // 25

__global__ __launch_bounds__(256) void scan1_kernel(const int* __restrict__ deg,
                                                    int* __restrict__ row_ptr,
                                                    int* __restrict__ block_sums,
                                                    float* __restrict__ dinv) {
    __shared__ int ldata[256];
    const int t = threadIdx.x;
    const int base = blockIdx.x * SCAN_ELEMS;
    int v[8];
    int sum = 0;
#pragma unroll
    for (int j = 0; j < 8; ++j) {
        int idx = base + t * 8 + j;
        v[j] = (idx < NN) ? deg[idx] : 0;
        if (idx < NN) dinv[idx] = rsqrtf((float)v[j] + 1.0f);  // +1 self-loop
        sum += v[j];
    }
    ldata[t] = sum;
    __syncthreads();
    for (int off = 1; off < 256; off <<= 1) {
        int x = (t >= off) ? ldata[t - off] : 0;
        __syncthreads();
        if (t >= off) ldata[t] += x;
        __syncthreads();
    }
    int excl = ldata[t] - sum;
    if (t == 255) block_sums[blockIdx.x] = ldata[255];
    int run = excl;
#pragma unroll
    for (int j = 0; j < 8; ++j) {
        int idx = base + t * 8 + j;
        if (idx < NN) row_ptr[idx] = run;
        run += v[j];
    }
}

__global__ __launch_bounds__(256) void scan3_kernel(int* __restrict__ row_ptr,
                                                    const int* __restrict__ block_sums) {
    int add = 0;
    for (int i = 0; i < SCAN_BLOCKS; ++i) add += (i < blockIdx.x) ? block_sums[i] : 0;
    const int base = blockIdx.x * SCAN_ELEMS;
#pragma unroll
    for (int j = 0; j < 8; ++j) {
        int idx = base + threadIdx.x * 8 + j;
        if (idx < NN) row_ptr[idx] += add;
    }
    if (blockIdx.x == 0 && threadIdx.x == 0) row_ptr[NN] = NE;
}

// ---------------- fill CSR (ushort src only; weight recomputed later) ----------------
__global__ __launch_bounds__(256) void fill_direct_kernel(const int* __restrict__ ei,
                                                          const int* __restrict__ row_ptr,
                                                          int* __restrict__ fill,
                                                          ushort* __restrict__ csr_src) {
    const int i64 = detect_i64(ei);
    int e = blockIdx.x * 256 + threadIdx.x;
    if (e >= NE) return;
    int s = i64 ? ei[2 * e] : ei[e];
    int d = i64 ? ei[2 * (NE + e)] : ei[NE + e];
    s = min(max(s, 0), NN - 1);
    d = min(max(d, 0), NN - 1);
    int pos = atomicAdd(&fill[d], 1);
    csr_src[row_ptr[d] + pos] = (ushort)s;
}

// ---------------- weight transpose + bf16 convert, all 3 weights ----------------
__global__ __launch_bounds__(128) void wtrans_all_kernel(
    const float* __restrict__ W1, const float* __restrict__ W2, const float* __restrict__ W3,
    ushort* __restrict__ Wt1, ushort* __restrict__ Wt2, ushort* __restrict__ Wt3) {
    __shared__ float tile[8][132];
    const int b = blockIdx.x;
    const float* W;
    ushort* Wt;
    int K, k0;
    if (b < 64) {
        W = W1; Wt = Wt1; K = NF; k0 = b * 8;
    } else if (b < 80) {
        W = W2; Wt = Wt2; K = NH; k0 = (b - 64) * 8;
    } else {
        W = W3; Wt = Wt3; K = NH; k0 = (b - 80) * 8;
    }
#pragma unroll
    for (int i = 0; i < 8; ++i) {
        int idx = threadIdx.x + i * 128;
        int r = idx >> 7;
        int c = idx & 127;
        tile[r][c] = W[(size_t)(k0 + r) * NH + c];
    }
    __syncthreads();
    const int c = threadIdx.x;
    uint4 o;
    o.x = pk2(tile[0][c], tile[1][c]);
    o.y = pk2(tile[2][c], tile[3][c]);
    o.z = pk2(tile[4][c], tile[5][c]);
    o.w = pk2(tile[6][c], tile[7][c]);
    *(uint4*)&Wt[(size_t)c * K + k0] = o;
}

// ---------------- MFMA GEMM: H[nrows x 128](bf16) = A[nrows x K] @ W ----------------
// BM=32, BK=64, XOR-swizzled LDS — R4/R7-proven structure.
#define BM 32

template <int A_F32>
__global__ __launch_bounds__(256) void gemm_mfma_kernel(const void* __restrict__ Ap,
                                                        const ushort* __restrict__ Wt,
                                                        ushort* __restrict__ Hout, int nrows,
                                                        int K) {
    __shared__ __align__(16) ushort smem[BM * 64 + NH * 64];
    ushort* As = smem;            // [32][64] bf16, swizzled
    ushort* Bs = smem + BM * 64;  // [128][64] bf16, swizzled
    const int tid = threadIdx.x;
    const int wave = tid >> 6;
    const int lane = tid & 63;
    const int l15 = lane & 15;
    const int l4 = lane >> 4;
    const int brow = blockIdx.x * BM;

    f32x4 zero4 = {0.f, 0.f, 0.f, 0.f};
    f32x4 acc[2][2];
#pragma unroll
    for (int rb = 0; rb < 2; ++rb)
#pragma unroll
        for (int cb = 0; cb < 2; ++cb) acc[rb][cb] = zero4;

    for (int k0 = 0; k0 < K; k0 += 64) {
        // stage A tile: 32 rows x 8 chunks(16B), one chunk per thread
        {
            int r = tid >> 3;
            int s = tid & 7;
            int gr = brow + r;
            uint4 w = make_uint4(0, 0, 0, 0);
            if (A_F32) {
                if (gr < nrows) {
                    const float* A = (const float*)Ap;
                    float4 f0 = *(const float4*)(A + (size_t)gr * K + k0 + s * 8);
                    float4 f1 = *(const float4*)(A + (size_t)gr * K + k0 + s * 8 + 4);
                    w.x = pk2(f0.x, f0.y);
                    w.y = pk2(f0.z, f0.w);
                    w.z = pk2(f1.x, f1.y);
                    w.w = pk2(f1.z, f1.w);
                }
            } else {
                if (gr < nrows) {
                    const ushort* A = (const ushort*)Ap;
                    w = *(const uint4*)(A + (size_t)gr * K + k0 + s * 8);
                }
            }
            *(uint4*)&As[r * 64 + ((s ^ (r & 7)) * 8)] = w;
        }
        // stage B tile: 128 rows x 8 chunks, 4 chunks per thread
#pragma unroll
        for (int i = 0; i < 4; ++i) {
            int idx = tid + i * 256;
            int r = idx >> 3;
            int s = idx & 7;
            uint4 w = *(const uint4*)&Wt[(size_t)r * K + k0 + s * 8];
            *(uint4*)&Bs[r * 64 + ((s ^ (r & 7)) * 8)] = w;
        }
        __syncthreads();
#pragma unroll
        for (int ks = 0; ks < 2; ++ks) {
            short8_t af[2], bf[2];
#pragma unroll
            for (int rb = 0; rb < 2; ++rb) {
                int r = rb * 16 + l15;
                af[rb] = *(const short8_t*)&As[r * 64 + (((ks * 4 + l4) ^ (r & 7)) * 8)];
            }
#pragma unroll
            for (int cb = 0; cb < 2; ++cb) {
                int r = wave * 32 + cb * 16 + l15;
                bf[cb] = *(const short8_t*)&Bs[r * 64 + (((ks * 4 + l4) ^ (r & 7)) * 8)];
            }
#pragma unroll
            for (int rb = 0; rb < 2; ++rb)
#pragma unroll
                for (int cb = 0; cb < 2; ++cb)
                    acc[rb][cb] = __builtin_amdgcn_mfma_f32_16x16x32_bf16(af[rb], bf[cb],
                                                                          acc[rb][cb], 0, 0, 0);
        }
        __syncthreads();
    }

    // epilogue: assemble bf16 tile in LDS [32][136], then coalesced store
    ushort* Es = smem;
#pragma unroll
    for (int rb = 0; rb < 2; ++rb)
#pragma unroll
        for (int cb = 0; cb < 2; ++cb)
#pragma unroll
            for (int j = 0; j < 4; ++j) {
                int r = rb * 16 + l4 * 4 + j;
                int c = wave * 32 + cb * 16 + l15;
                Es[r * 136 + c] = f2bf(acc[rb][cb][j]);
            }
    __syncthreads();
#pragma unroll
    for (int i = 0; i < 2; ++i) {
        int idx = tid + i * 256;
        int r = idx >> 4;
        int s = idx & 15;
        if (brow + r < nrows)
            *(uint4*)&Hout[(size_t)(brow + r) * NH + s * 8] = *(const uint4*)&Es[r * 136 + s * 8];
    }
}

__device__ inline void fma8(float* acc, float w, uint4 v) {
    acc[0] += w * bflo(v.x);
    acc[1] += w * bfhi(v.x);
    acc[2] += w * bflo(v.y);
    acc[3] += w * bfhi(v.y);
    acc[4] += w * bflo(v.z);
    acc[5] += w * bfhi(v.z);
    acc[6] += w * bflo(v.w);
    acc[7] += w * bfhi(v.w);
}

// ---------------- aggregate: full-row CSR gather; MODE 0 = bf16+relu,
// MODE 1 = fused classifier + log_softmax ----------------
template <int MODE>
__global__ __launch_bounds__(256) void aggregate_kernel(
    const ushort* __restrict__ h, const int* __restrict__ row_ptr,
    const ushort* __restrict__ csr_src, const float* __restrict__ dinv,
    const float* __restrict__ b, const float* __restrict__ Wl, const float* __restrict__ bl,
    void* __restrict__ outp) {
    __shared__ float Wls[MODE ? NH * NC + NC : 1];
    if (MODE) {
        for (int i = threadIdx.x; i < NH * NC; i += 256) Wls[i] = Wl[i];
        if (threadIdx.x < NC) Wls[NH * NC + threadIdx.x] = bl[threadIdx.x];
        __syncthreads();
    }
    const int node = (blockIdx.x * 256 + threadIdx.x) >> 6;  // one wave per node
    if (node >= NN) return;
    const int lane = threadIdx.x & 63;
    const int g = lane >> 4;    // edge group 0..3
    const int li = lane & 15;   // feature chunk (8 bf16)
    const uint4* __restrict__ hp = (const uint4*)h;
    const int beg = row_ptr[node];
    const int end = row_ptr[node + 1];
    const float dn = dinv[node];

    float acc[8];
#pragma unroll
    for (int k = 0; k < 8; ++k) acc[k] = 0.f;

    for (int e0 = beg; e0 < end; e0 += 16) {
        int eb = e0 + g * 4;  // this group's 4 consecutive edges
        if (eb < end) {       // group-uniform branch; loads unconditional (padded csr)
            int s0 = min((int)csr_src[eb + 0], NN - 1);
            int s1 = min((int)csr_src[eb + 1], NN - 1);
            int s2 = min((int)csr_src[eb + 2], NN - 1);
            int s3 = min((int)csr_src[eb + 3], NN - 1);
            float w0 = dinv[s0] * dn;
            float w1 = (eb + 1 < end) ? dinv[s1] * dn : 0.f;
            float w2 = (eb + 2 < end) ? dinv[s2] * dn : 0.f;
            float w3 = (eb + 3 < end) ? dinv[s3] * dn : 0.f;
            uint4 v0 = hp[(size_t)s0 * 16 + li];
            uint4 v1 = hp[(size_t)s1 * 16 + li];
            uint4 v2 = hp[(size_t)s2 * 16 + li];
            uint4 v3 = hp[(size_t)s3 * 16 + li];
            fma8(acc, w0, v0);
            fma8(acc, w1, v1);
            fma8(acc, w2, v2);
            fma8(acc, w3, v3);
        }
    }
#pragma unroll
    for (int k = 0; k < 8; ++k) {
        acc[k] += __shfl_xor(acc[k], 16);
        acc[k] += __shfl_xor(acc[k], 32);
    }
    if (g == 0) {
        uint4 hv = hp[(size_t)node * 16 + li];
        float sl = dn * dn;
        float v[8];
        float4 b0 = *(const float4*)(b + li * 8);
        float4 b1 = *(const float4*)(b + li * 8 + 4);
        v[0] = acc[0] + sl * bflo(hv.x) + b0.x;
        v[1] = acc[1] + sl * bfhi(hv.x) + b0.y;
        v[2] = acc[2] + sl * bflo(hv.y) + b0.z;
        v[3] = acc[3] + sl * bfhi(hv.y) + b0.w;
        v[4] = acc[4] + sl * bflo(hv.z) + b1.x;
        v[5] = acc[5] + sl * bfhi(hv.z) + b1.y;
        v[6] = acc[6] + sl * bflo(hv.w) + b1.z;
        v[7] = acc[7] + sl * bfhi(hv.w) + b1.w;
        if (MODE == 0) {
#pragma unroll
            for (int k = 0; k < 8; ++k) v[k] = fmaxf(v[k], 0.f);
            ushort* out = (ushort*)outp;
            uint4 o;
            o.x = pk2(v[0], v[1]);
            o.y = pk2(v[2], v[3]);
            o.z = pk2(v[4], v[5]);
            o.w = pk2(v[6], v[7]);
            *(uint4*)(out + (size_t)node * NH + li * 8) = o;
        } else {
            float lg[NC];
#pragma unroll
            for (int c = 0; c < NC; ++c) lg[c] = 0.f;
#pragma unroll
            for (int j = 0; j < 8; ++j) {
                int f = li * 8 + j;
#pragma unroll
                for (int c = 0; c < NC; ++c) lg[c] += v[j] * Wls[f * NC + c];
            }
#pragma unroll
            for (int c = 0; c < NC; ++c) {
                lg[c] += __shfl_xor(lg[c], 1);
                lg[c] += __shfl_xor(lg[c], 2);
                lg[c] += __shfl_xor(lg[c], 4);
                lg[c] += __shfl_xor(lg[c], 8);
                lg[c] += Wls[NH * NC + c];
            }
            float m = lg[0];
#pragma unroll
            for (int c = 1; c < NC; ++c) m = fmaxf(m, lg[c]);
            float s = 0.f;
#pragma unroll
            for (int c = 0; c < NC; ++c) s += expf(lg[c] - m);
            float lse = m + logf(s);
            if (li < NC) {
                float* out = (float*)outp;
                out[(size_t)node * NC + li] = lg[li] - lse;
            }
        }
    }
}

extern "C" void kernel_launch(void* const* d_in, const int* in_sizes, int n_in,
                              void* d_out, int out_size, void* d_ws, size_t ws_size,
                              hipStream_t stream) {
    const float* x = (const float*)d_in[0];
    const int* ei = (const int*)d_in[1];
    const float* W1 = (const float*)d_in[2];
    const float* b1 = (const float*)d_in[3];
    const float* W2 = (const float*)d_in[4];
    const float* b2 = (const float*)d_in[5];
    const float* W3 = (const float*)d_in[6];
    const float* b3 = (const float*)d_in[7];
    const float* Wl = (const float*)d_in[8];
    const float* bl = (const float*)d_in[9];
    float* out = (float*)d_out;

    char* ws = (char*)d_ws;
    size_t off = 0;
    auto alloc = [&](size_t bytes) {
        void* p = ws + off;
        off = (off + bytes + 255) & ~(size_t)255;
        return p;
    };
    int* degfill = (int*)alloc((size_t)2 * NN * 4);  // deg | fill, one memset
    int* deg = degfill;
    int* fill = degfill + NN;
    float* dinv = (float*)alloc((size_t)NN * 4);
    int* row_ptr = (int*)alloc((size_t)(NN + 1) * 4);
    int* block_sums = (int*)alloc((size_t)SCAN_BLOCKS * 4 + 256);
    ushort* csr_src = (ushort*)alloc((size_t)(NE + 32) * 2);  // src only, +pad
    ushort* h = (ushort*)alloc((size_t)NN * NH * 2);       // bf16 pre-aggregation features
    ushort* act_bf = (ushort*)alloc((size_t)NN * NH * 2);  // bf16 activations
    ushort* Wt1 = (ushort*)alloc((size_t)NF * NH * 2);
    ushort* Wt2 = (ushort*)alloc((size_t)NH * NH * 2);
    ushort* Wt3 = (ushort*)alloc((size_t)NH * NH * 2);
    (void)ws_size;

    // --- CSR build (once, reused for 3 layers) ---
    hipMemsetAsync(degfill, 0, (size_t)2 * NN * 4, stream);
    deg_direct_kernel<<<(NE + 255) / 256, 256, 0, stream>>>(ei, deg);
    scan1_kernel<<<SCAN_BLOCKS, 256, 0, stream>>>(deg, row_ptr, block_sums, dinv);
    scan3_kernel<<<SCAN_BLOCKS, 256, 0, stream>>>(row_ptr, block_sums);
    fill_direct_kernel<<<(NE + 255) / 256, 256, 0, stream>>>(ei, row_ptr, fill, csr_src);
    wtrans_all_kernel<<<96, 128, 0, stream>>>(W1, W2, W3, Wt1, Wt2, Wt3);

    const int gemm_grid = (NN + BM - 1) / BM;
    const int agg_grid = (NN * 64 + 255) / 256;

    // layer 1
    gemm_mfma_kernel<1><<<gemm_grid, 256, 0, stream>>>(x, Wt1, h, NN, NF);
    aggregate_kernel<0><<<agg_grid, 256, 0, stream>>>(h, row_ptr, csr_src, dinv, b1, nullptr,
                                                      nullptr, act_bf);
    // layer 2
    gemm_mfma_kernel<0><<<gemm_grid, 256, 0, stream>>>(act_bf, Wt2, h, NN, NH);
    aggregate_kernel<0><<<agg_grid, 256, 0, stream>>>(h, row_ptr, csr_src, dinv, b2, nullptr,
                                                      nullptr, act_bf);
    // layer 3: aggregate + classifier + log_softmax fused, writes d_out directly
    gemm_mfma_kernel<0><<<gemm_grid, 256, 0, stream>>>(act_bf, Wt3, h, NN, NH);
    aggregate_kernel<1><<<agg_grid, 256, 0, stream>>>(h, row_ptr, csr_src, dinv, b3, Wl, bl,
                                                      out);
}

// Round 12
// 256.122 us; speedup vs baseline: 2.0529x; 1.0512x over previous
//
#include <hip/hip_runtime.h>
#include <math.h>

#define NN 50000
#define NF 512
#define NH 128
#define NC 10
#define NE 800000

typedef __attribute__((ext_vector_type(8))) short short8_t;
typedef __attribute__((ext_vector_type(4))) float f32x4;

__device__ inline ushort f2bf(float f) {
    union { float f; uint u; } v;
    v.f = f;
    uint r = v.u + 0x7FFF + ((v.u >> 16) & 1);
    return (ushort)(r >> 16);
}
__device__ inline uint pk2(float a, float b) {
    return (uint)f2bf(a) | ((uint)f2bf(b) << 16);
}
__device__ inline float bflo(uint u) {
    union { uint u; float f; } v;
    v.u = u << 16;
    return v.f;
}
__device__ inline float bfhi(uint u) {
    union { uint u; float f; } v;
    v.u = u & 0xFFFF0000u;
    return v.f;
}

// Block-local int64-vs-int32 detection: if ei is int64 (values < 2^31), every odd
// 32-bit word of the first 1024 pairs is 0. Each block computes the same flag.
__device__ inline int detect_i64(const int* __restrict__ ei) {
    __shared__ int s_nz;
    if (threadIdx.x == 0) s_nz = 0;
    __syncthreads();
    int v = 0;
    for (int i = threadIdx.x; i < 1024; i += 256) v |= ei[2 * i + 1];
    if (v) s_nz = 1;  // benign race
    __syncthreads();
    return (s_nz == 0) ? 1 : 0;
}

// ---------------- degree count, straight from ei ----------------
__global__ __launch_bounds__(256) void deg_direct_kernel(const int* __restrict__ ei,
                                                         int* __restrict__ deg) {
    const int i64 = detect_i64(ei);
    int e = blockIdx.x * 256 + threadIdx.x;
    if (e >= NE) return;
    int d = i64 ? ei[2 * (NE + e)] : ei[NE + e];
    d = min(max(d, 0), NN - 1);
    atomicAdd(&deg[d], 1);
}

// ---------------- exclusive prefix sum of deg -> row_ptr (+dinv) ----------------
#define SCAN_ELEMS 2048
#define SCAN_BLOCKS ((NN + SCAN_ELEMS - 1) / SCAN_ELEMS)  // 25

__global__ __launch_bounds__(256) void scan1_kernel(const int* __restrict__ deg,
                                                    int* __restrict__ row_ptr,
                                                    int* __restrict__ block_sums,
                                                    float* __restrict__ dinv) {
    __shared__ int ldata[256];
    const int t = threadIdx.x;
    const int base = blockIdx.x * SCAN_ELEMS;
    int v[8];
    int sum = 0;
#pragma unroll
    for (int j = 0; j < 8; ++j) {
        int idx = base + t * 8 + j;
        v[j] = (idx < NN) ? deg[idx] : 0;
        if (idx < NN) dinv[idx] = rsqrtf((float)v[j] + 1.0f);  // +1 self-loop
        sum += v[j];
    }
    ldata[t] = sum;
    __syncthreads();
    for (int off = 1; off < 256; off <<= 1) {
        int x = (t >= off) ? ldata[t - off] : 0;
        __syncthreads();
        if (t >= off) ldata[t] += x;
        __syncthreads();
    }
    int excl = ldata[t] - sum;
    if (t == 255) block_sums[blockIdx.x] = ldata[255];
    int run = excl;
#pragma unroll
    for (int j = 0; j < 8; ++j) {
        int idx = base + t * 8 + j;
        if (idx < NN) row_ptr[idx] = run;
        run += v[j];
    }
}

// scan3 also does scan2's job: each block prefix-sums block_sums[0..blockIdx) itself.
__global__ __launch_bounds__(256) void scan3_kernel(int* __restrict__ row_ptr,
                                                    const int* __restrict__ block_sums) {
    int add = 0;
    for (int i = 0; i < SCAN_BLOCKS; ++i) add += (i < blockIdx.x) ? block_sums[i] : 0;
    const int base = blockIdx.x * SCAN_ELEMS;
#pragma unroll
    for (int j = 0; j < 8; ++j) {
        int idx = base + threadIdx.x * 8 + j;
        if (idx < NN) row_ptr[idx] += add;
    }
    if (blockIdx.x == 0 && threadIdx.x == 0) row_ptr[NN] = NE;
}

// ---------------- fill CSR straight from ei (packed int2 {src, w_bits}) ----------------
__global__ __launch_bounds__(256) void fill_direct_kernel(
    const int* __restrict__ ei, const float* __restrict__ dinv,
    const int* __restrict__ row_ptr, int* __restrict__ fill, int2* __restrict__ csr) {
    const int i64 = detect_i64(ei);
    int e = blockIdx.x * 256 + threadIdx.x;
    if (e >= NE) return;
    int s = i64 ? ei[2 * e] : ei[e];
    int d = i64 ? ei[2 * (NE + e)] : ei[NE + e];
    s = min(max(s, 0), NN - 1);
    d = min(max(d, 0), NN - 1);
    int pos = atomicAdd(&fill[d], 1);
    int idx = row_ptr[d] + pos;
    float w = dinv[s] * dinv[d];
    csr[idx] = make_int2(s, __float_as_int(w));
}

// ---------------- weight transpose + bf16 convert, all 3 weights ----------------
__global__ __launch_bounds__(128) void wtrans_all_kernel(
    const float* __restrict__ W1, const float* __restrict__ W2, const float* __restrict__ W3,
    ushort* __restrict__ Wt1, ushort* __restrict__ Wt2, ushort* __restrict__ Wt3) {
    __shared__ float tile[8][132];
    const int b = blockIdx.x;
    const float* W;
    ushort* Wt;
    int K, k0;
    if (b < 64) {
        W = W1; Wt = Wt1; K = NF; k0 = b * 8;
    } else if (b < 80) {
        W = W2; Wt = Wt2; K = NH; k0 = (b - 64) * 8;
    } else {
        W = W3; Wt = Wt3; K = NH; k0 = (b - 80) * 8;
    }
#pragma unroll
    for (int i = 0; i < 8; ++i) {
        int idx = threadIdx.x + i * 128;
        int r = idx >> 7;
        int c = idx & 127;
        tile[r][c] = W[(size_t)(k0 + r) * NH + c];
    }
    __syncthreads();
    const int c = threadIdx.x;
    uint4 o;
    o.x = pk2(tile[0][c], tile[1][c]);
    o.y = pk2(tile[2][c], tile[3][c]);
    o.z = pk2(tile[4][c], tile[5][c]);
    o.w = pk2(tile[6][c], tile[7][c]);
    *(uint4*)&Wt[(size_t)c * K + k0] = o;
}

// ---------------- MFMA GEMM: H[nrows x 128](bf16) = A[nrows x K] @ W ----------------
// BM=32, BK=64, XOR-swizzled LDS (16B chunk index ^ (row&7)) — R4/R7-proven structure.
#define BM 32

template <int A_F32>
__global__ __launch_bounds__(256) void gemm_mfma_kernel(const void* __restrict__ Ap,
                                                        const ushort* __restrict__ Wt,
                                                        ushort* __restrict__ Hout, int nrows,
                                                        int K) {
    __shared__ __align__(16) ushort smem[BM * 64 + NH * 64];  // As | Bs; reused as epilogue
    ushort* As = smem;            // [32][64] bf16, swizzled
    ushort* Bs = smem + BM * 64;  // [128][64] bf16, swizzled
    const int tid = threadIdx.x;
    const int wave = tid >> 6;
    const int lane = tid & 63;
    const int l15 = lane & 15;
    const int l4 = lane >> 4;
    const int brow = blockIdx.x * BM;

    f32x4 zero4 = {0.f, 0.f, 0.f, 0.f};
    f32x4 acc[2][2];
#pragma unroll
    for (int rb = 0; rb < 2; ++rb)
#pragma unroll
        for (int cb = 0; cb < 2; ++cb) acc[rb][cb] = zero4;

    for (int k0 = 0; k0 < K; k0 += 64) {
        // stage A tile: 32 rows x 8 chunks(16B), one chunk per thread
        {
            int r = tid >> 3;
            int s = tid & 7;
            int gr = brow + r;
            uint4 w = make_uint4(0, 0, 0, 0);
            if (A_F32) {
                if (gr < nrows) {
                    const float* A = (const float*)Ap;
                    float4 f0 = *(const float4*)(A + (size_t)gr * K + k0 + s * 8);
                    float4 f1 = *(const float4*)(A + (size_t)gr * K + k0 + s * 8 + 4);
                    w.x = pk2(f0.x, f0.y);
                    w.y = pk2(f0.z, f0.w);
                    w.z = pk2(f1.x, f1.y);
                    w.w = pk2(f1.z, f1.w);
                }
            } else {
                if (gr < nrows) {
                    const ushort* A = (const ushort*)Ap;
                    w = *(const uint4*)(A + (size_t)gr * K + k0 + s * 8);
                }
            }
            *(uint4*)&As[r * 64 + ((s ^ (r & 7)) * 8)] = w;
        }
        // stage B tile: 128 rows x 8 chunks, 4 chunks per thread
#pragma unroll
        for (int i = 0; i < 4; ++i) {
            int idx = tid + i * 256;
            int r = idx >> 3;
            int s = idx & 7;
            uint4 w = *(const uint4*)&Wt[(size_t)r * K + k0 + s * 8];
            *(uint4*)&Bs[r * 64 + ((s ^ (r & 7)) * 8)] = w;
        }
        __syncthreads();
#pragma unroll
        for (int ks = 0; ks < 2; ++ks) {
            short8_t af[2], bf[2];
#pragma unroll
            for (int rb = 0; rb < 2; ++rb) {
                int r = rb * 16 + l15;
                af[rb] = *(const short8_t*)&As[r * 64 + (((ks * 4 + l4) ^ (r & 7)) * 8)];
            }
#pragma unroll
            for (int cb = 0; cb < 2; ++cb) {
                int r = wave * 32 + cb * 16 + l15;
                bf[cb] = *(const short8_t*)&Bs[r * 64 + (((ks * 4 + l4) ^ (r & 7)) * 8)];
            }
#pragma unroll
            for (int rb = 0; rb < 2; ++rb)
#pragma unroll
                for (int cb = 0; cb < 2; ++cb)
                    acc[rb][cb] = __builtin_amdgcn_mfma_f32_16x16x32_bf16(af[rb], bf[cb],
                                                                          acc[rb][cb], 0, 0, 0);
        }
        __syncthreads();
    }

    // epilogue: assemble bf16 tile in LDS [32][136], then coalesced store
    ushort* Es = smem;
#pragma unroll
    for (int rb = 0; rb < 2; ++rb)
#pragma unroll
        for (int cb = 0; cb < 2; ++cb)
#pragma unroll
            for (int j = 0; j < 4; ++j) {
                int r = rb * 16 + l4 * 4 + j;
                int c = wave * 32 + cb * 16 + l15;
                Es[r * 136 + c] = f2bf(acc[rb][cb][j]);
            }
    __syncthreads();
#pragma unroll
    for (int i = 0; i < 2; ++i) {
        int idx = tid + i * 256;
        int r = idx >> 4;
        int s = idx & 15;
        if (brow + r < nrows)
            *(uint4*)&Hout[(size_t)(brow + r) * NH + s * 8] = *(const uint4*)&Es[r * 136 + s * 8];
    }
}

// ---------------- aggregate: packed-CSR gather + self-loop + bias; MODE 0 = bf16+relu,
// MODE 1 = fused classifier + log_softmax. ----------------
__device__ inline void fma8(float* acc, float w, uint4 v) {
    acc[0] += w * bflo(v.x);
    acc[1] += w * bfhi(v.x);
    acc[2] += w * bflo(v.y);
    acc[3] += w * bfhi(v.y);
    acc[4] += w * bflo(v.z);
    acc[5] += w * bfhi(v.z);
    acc[6] += w * bflo(v.w);
    acc[7] += w * bfhi(v.w);
}

template <int MODE>
__global__ __launch_bounds__(256) void aggregate_kernel(
    const ushort* __restrict__ h, const int* __restrict__ row_ptr,
    const int2* __restrict__ csr, const float* __restrict__ dinv, const float* __restrict__ b,
    const float* __restrict__ Wl, const float* __restrict__ bl, void* __restrict__ outp) {
    __shared__ float Wls[MODE ? NH * NC + NC : 1];
    if (MODE) {
        for (int i = threadIdx.x; i < NH * NC; i += 256) Wls[i] = Wl[i];
        if (threadIdx.x < NC) Wls[NH * NC + threadIdx.x] = bl[threadIdx.x];
        __syncthreads();
    }
    const int node = (blockIdx.x * 256 + threadIdx.x) >> 6;  // one wave per node
    if (node >= NN) return;
    const int lane = threadIdx.x & 63;
    const int g = lane >> 4;    // edge group 0..3
    const int li = lane & 15;   // feature chunk (8 bf16)
    const uint4* __restrict__ hp = (const uint4*)h;
    const int beg = row_ptr[node];
    const int end = row_ptr[node + 1];

    float acc[8];
#pragma unroll
    for (int k = 0; k < 8; ++k) acc[k] = 0.f;

    for (int e0 = beg; e0 < end; e0 += 16) {
        int eb = e0 + g * 4;  // this group's 4 consecutive edges (32B contiguous)
        if (eb < end) {       // group-uniform branch
            int2 p0 = csr[eb + 0];
            int2 p1 = csr[eb + 1];
            int2 p2 = csr[eb + 2];
            int2 p3 = csr[eb + 3];
            int s0 = min(max(p0.x, 0), NN - 1);
            int s1 = min(max(p1.x, 0), NN - 1);
            int s2 = min(max(p2.x, 0), NN - 1);
            int s3 = min(max(p3.x, 0), NN - 1);
            float w0 = __int_as_float(p0.y);  // eb < end always
            float w1 = (eb + 1 < end) ? __int_as_float(p1.y) : 0.f;
            float w2 = (eb + 2 < end) ? __int_as_float(p2.y) : 0.f;
            float w3 = (eb + 3 < end) ? __int_as_float(p3.y) : 0.f;
            uint4 v0 = hp[(size_t)s0 * 16 + li];
            uint4 v1 = hp[(size_t)s1 * 16 + li];
            uint4 v2 = hp[(size_t)s2 * 16 + li];
            uint4 v3 = hp[(size_t)s3 * 16 + li];
            fma8(acc, w0, v0);
            fma8(acc, w1, v1);
            fma8(acc, w2, v2);
            fma8(acc, w3, v3);
        }
    }
    // reduce across the 4 groups
#pragma unroll
    for (int k = 0; k < 8; ++k) {
        acc[k] += __shfl_xor(acc[k], 16);
        acc[k] += __shfl_xor(acc[k], 32);
    }
    if (g == 0) {
        uint4 hv = hp[(size_t)node * 16 + li];
        float di = dinv[node];
        float sl = di * di;
        float v[8];
        float4 b0 = *(const float4*)(b + li * 8);
        float4 b1 = *(const float4*)(b + li * 8 + 4);
        v[0] = acc[0] + sl * bflo(hv.x) + b0.x;
        v[1] = acc[1] + sl * bfhi(hv.x) + b0.y;
        v[2] = acc[2] + sl * bflo(hv.y) + b0.z;
        v[3] = acc[3] + sl * bfhi(hv.y) + b0.w;
        v[4] = acc[4] + sl * bflo(hv.z) + b1.x;
        v[5] = acc[5] + sl * bfhi(hv.z) + b1.y;
        v[6] = acc[6] + sl * bflo(hv.w) + b1.z;
        v[7] = acc[7] + sl * bfhi(hv.w) + b1.w;
        if (MODE == 0) {
#pragma unroll
            for (int k = 0; k < 8; ++k) v[k] = fmaxf(v[k], 0.f);
            ushort* out = (ushort*)outp;
            uint4 o;
            o.x = pk2(v[0], v[1]);
            o.y = pk2(v[2], v[3]);
            o.z = pk2(v[4], v[5]);
            o.w = pk2(v[6], v[7]);
            *(uint4*)(out + (size_t)node * NH + li * 8) = o;
        } else {
            // layer-3 epilogue (no relu) + classifier + log_softmax
            float lg[NC];
#pragma unroll
            for (int c = 0; c < NC; ++c) lg[c] = 0.f;
#pragma unroll
            for (int j = 0; j < 8; ++j) {
                int f = li * 8 + j;
#pragma unroll
                for (int c = 0; c < NC; ++c) lg[c] += v[j] * Wls[f * NC + c];
            }
#pragma unroll
            for (int c = 0; c < NC; ++c) {
                lg[c] += __shfl_xor(lg[c], 1);
                lg[c] += __shfl_xor(lg[c], 2);
                lg[c] += __shfl_xor(lg[c], 4);
                lg[c] += __shfl_xor(lg[c], 8);
                lg[c] += Wls[NH * NC + c];  // bias
            }
            float m = lg[0];
#pragma unroll
            for (int c = 1; c < NC; ++c) m = fmaxf(m, lg[c]);
            float s = 0.f;
#pragma unroll
            for (int c = 0; c < NC; ++c) s += expf(lg[c] - m);
            float lse = m + logf(s);
            if (li < NC) {
                float* out = (float*)outp;
                out[(size_t)node * NC + li] = lg[li] - lse;
            }
        }
    }
}

extern "C" void kernel_launch(void* const* d_in, const int* in_sizes, int n_in,
                              void* d_out, int out_size, void* d_ws, size_t ws_size,
                              hipStream_t stream) {
    const float* x = (const float*)d_in[0];
    const int* ei = (const int*)d_in[1];
    const float* W1 = (const float*)d_in[2];
    const float* b1 = (const float*)d_in[3];
    const float* W2 = (const float*)d_in[4];
    const float* b2 = (const float*)d_in[5];
    const float* W3 = (const float*)d_in[6];
    const float* b3 = (const float*)d_in[7];
    const float* Wl = (const float*)d_in[8];
    const float* bl = (const float*)d_in[9];
    float* out = (float*)d_out;

    char* ws = (char*)d_ws;
    size_t off = 0;
    auto alloc = [&](size_t bytes) {
        void* p = ws + off;
        off = (off + bytes + 255) & ~(size_t)255;
        return p;
    };
    int* degfill = (int*)alloc((size_t)2 * NN * 4);  // deg | fill, one memset
    int* deg = degfill;
    int* fill = degfill + NN;
    float* dinv = (float*)alloc((size_t)NN * 4);
    int* row_ptr = (int*)alloc((size_t)(NN + 1) * 4);
    int* block_sums = (int*)alloc((size_t)SCAN_BLOCKS * 4 + 256);
    int2* csr = (int2*)alloc((size_t)(NE + 16) * 8);  // packed {src, w_bits}, +16 pad
    ushort* h = (ushort*)alloc((size_t)NN * NH * 2);       // bf16 pre-aggregation features
    ushort* act_bf = (ushort*)alloc((size_t)NN * NH * 2);  // bf16 activations
    ushort* Wt1 = (ushort*)alloc((size_t)NF * NH * 2);
    ushort* Wt2 = (ushort*)alloc((size_t)NH * NH * 2);
    ushort* Wt3 = (ushort*)alloc((size_t)NH * NH * 2);
    (void)ws_size;

    // --- CSR build (once, reused for 3 layers) ---
    hipMemsetAsync(degfill, 0, (size_t)2 * NN * 4, stream);
    deg_direct_kernel<<<(NE + 255) / 256, 256, 0, stream>>>(ei, deg);
    scan1_kernel<<<SCAN_BLOCKS, 256, 0, stream>>>(deg, row_ptr, block_sums, dinv);
    scan3_kernel<<<SCAN_BLOCKS, 256, 0, stream>>>(row_ptr, block_sums);
    fill_direct_kernel<<<(NE + 255) / 256, 256, 0, stream>>>(ei, dinv, row_ptr, fill, csr);
    wtrans_all_kernel<<<96, 128, 0, stream>>>(W1, W2, W3, Wt1, Wt2, Wt3);

    const int gemm_grid = (NN + BM - 1) / BM;
    const int agg_grid = (NN * 64 + 255) / 256;

    // layer 1
    gemm_mfma_kernel<1><<<gemm_grid, 256, 0, stream>>>(x, Wt1, h, NN, NF);
    aggregate_kernel<0><<<agg_grid, 256, 0, stream>>>(h, row_ptr, csr, dinv, b1, nullptr,
                                                      nullptr, act_bf);
    // layer 2
    gemm_mfma_kernel<0><<<gemm_grid, 256, 0, stream>>>(act_bf, Wt2, h, NN, NH);
    aggregate_kernel<0><<<agg_grid, 256, 0, stream>>>(h, row_ptr, csr, dinv, b2, nullptr,
                                                      nullptr, act_bf);
    // layer 3: aggregate + classifier + log_softmax fused, writes d_out directly
    gemm_mfma_kernel<0><<<gemm_grid, 256, 0, stream>>>(act_bf, Wt3, h, NN, NH);
    aggregate_kernel<1><<<agg_grid, 256, 0, stream>>>(h, row_ptr, csr, dinv, b3, Wl, bl, out);
}